// Round 2
// baseline (14.168 us; speedup 1.0000x reference)
//
#include <hip/hip_runtime.h>

#define Bb 128
#define Cc 400
#define Ll 100
#define Pp 16

// ---------------------------------------------------------------------------
// Fused kernel: per-block (batch b), compute the 16x100 weight matrix in LDS
// via closed form, then out[b,c,l] = sum_i w[i,l] * x[b,c,i].
//
// Weight derivation (per b,l): q_j = 16*s + d*l + j (j in [0,d)), pos = q+8,
// t = (min(pos,1592)-8)/16, i0 = min(floor(t),98), fr = t-i0.
//   unclipped (q<1584): i0 = q>>4, fr = (q&15)/16
//   clipped   (q>=1584): i0 = 98, fr = 1 -> contributes 1.0 to w[99]
// w[i] = sum_{i0_j==i}(1-fr_j) + sum_{i0_j==i-1}(fr_j), scaled by 1/max(d,1).
// Each piece is a contiguous q-range -> triangular-number closed form.
// No workspace, no second kernel: nothing written outside d_out.
// ---------------------------------------------------------------------------
__global__ __launch_bounds__(256) void TemporalPooling_fused_kernel(
    const float* __restrict__ x, const int* __restrict__ seg,
    float* __restrict__ out) {
  __shared__ float w[Ll * Pp];   // [i][l], 6.4 KiB

  const int b   = blockIdx.y;
  const int tid = threadIdx.x;

  const int s = seg[2 * b];
  const int e = seg[2 * b + 1];
  const int d = e - s;
  const float inv = 1.0f / (float)max(d, 1);

  // ---- phase 1: weights into LDS (all 256 threads, 7 iters) ----
  for (int idx = tid; idx < Ll * Pp; idx += 256) {
    const int i = idx >> 4;   // 0..99
    const int l = idx & 15;   // 0..15

    const int a  = 16 * s + d * l;   // q_0
    const int ad = a + d;            // q end (exclusive)

    float sum = 0.0f;

    // part1: j with i0 == i  -> q in [16i, 16i+16) ∩ [a, ad) ∩ [0,1584)
    const int base1 = 16 * i;
    {
      const int lo = max(base1, a);
      const int hi = min(min(base1 + 16, ad), 1584);
      const int n = hi - lo;
      if (n > 0) {
        const int sq = (hi * (hi - 1) - lo * (lo - 1)) >> 1;  // sum of q
        sum += (float)n - (float)(sq - n * base1) * 0.0625f;  // sum(1-fr)
      }
    }
    // part2: j with i0 == i-1 -> q in [16(i-1), 16i) ∩ [a, ad) ∩ [0,1584)
    {
      const int base2 = base1 - 16;
      const int lo = max(base2, a);
      const int hi = min(min(base1, ad), 1584);
      const int n = hi - lo;
      if (n > 0) {
        const int sq = (hi * (hi - 1) - lo * (lo - 1)) >> 1;
        sum += (float)(sq - n * base2) * 0.0625f;             // sum(fr)
      }
    }
    // clipped tail: q >= 1584 -> fr = 1 -> +1 to w[99] per element
    if (i == Ll - 1) {
      const int nclip = ad - max(a, 1584);
      if (nclip > 0) sum += (float)nclip;
    }

    w[idx] = sum * inv;
  }
  __syncthreads();

  // ---- phase 2: pooling, one thread per (b,c) ----
  const int c = blockIdx.x * 256 + tid;
  if (c >= Cc) return;

  const float4* x4 = (const float4*)(x + ((size_t)b * Cc + c) * Ll);
  float4 xv[25];
#pragma unroll
  for (int q = 0; q < 25; ++q) xv[q] = x4[q];

  float acc[16];
#pragma unroll
  for (int l = 0; l < 16; ++l) acc[l] = 0.0f;

#pragma unroll
  for (int q = 0; q < 25; ++q) {
#pragma unroll
    for (int k = 0; k < 4; ++k) {
      const int i = q * 4 + k;
      const float xs = ((const float*)&xv[q])[k];
#pragma unroll
      for (int l = 0; l < 16; ++l)
        acc[l] = fmaf(w[i * 16 + l], xs, acc[l]);   // LDS broadcast read
    }
  }

  float4* o4 = (float4*)(out + ((size_t)b * Cc + c) * Pp);
#pragma unroll
  for (int t = 0; t < 4; ++t)
    o4[t] = make_float4(acc[4 * t], acc[4 * t + 1], acc[4 * t + 2],
                        acc[4 * t + 3]);
}

extern "C" void kernel_launch(void* const* d_in, const int* in_sizes, int n_in,
                              void* d_out, int out_size, void* d_ws,
                              size_t ws_size, hipStream_t stream) {
  const float* x = (const float*)d_in[0];   // (128,400,100) fp32
  const int* seg = (const int*)d_in[1];     // (128,2) int32
  float* out = (float*)d_out;               // (128,400,16) fp32
  (void)d_ws; (void)ws_size;                // unused — no workspace writes

  dim3 grid((Cc + 255) / 256, Bb);          // (2, 128)
  TemporalPooling_fused_kernel<<<grid, 256, 0, stream>>>(x, seg, out);
}